// Round 1
// baseline (122.597 us; speedup 1.0000x reference)
//
#include <hip/hip_runtime.h>

#define BN 8192
#define BD 256
#define NTRIALS 150

__device__ __forceinline__ float wave_reduce_sum(float v) {
    #pragma unroll
    for (int m = 32; m > 0; m >>= 1) v += __shfl_xor(v, m, 64);
    return v;
}

// Kernel 1: count genuine (tgt == 0) into ws counter. Single block, no atomics.
__global__ __launch_bounds__(1024) void count_genuine_kernel(
    const int* __restrict__ tgt, int* __restrict__ cnt)
{
    __shared__ int lds[16];
    const int t = threadIdx.x;
    int c = 0;
    for (int i = t; i < BN; i += 1024) c += (tgt[i] == 0) ? 1 : 0;
    #pragma unroll
    for (int m = 32; m > 0; m >>= 1) c += __shfl_xor(c, m, 64);
    if ((t & 63) == 0) lds[t >> 6] = c;
    __syncthreads();
    if (t == 0) {
        int s = 0;
        #pragma unroll
        for (int w = 0; w < 16; ++w) s += lds[w];
        *cnt = s;
    }
}

// Kernel 2: sq[i] = sum_d hd[i][d]^2. One wave per row.
__global__ __launch_bounds__(256) void sqnorm_kernel(
    const float* __restrict__ hd, float* __restrict__ sq)
{
    const int lane = threadIdx.x & 63;
    const int row  = blockIdx.x * 4 + (threadIdx.x >> 6);
    const float4 a = *reinterpret_cast<const float4*>(hd + row * BD + lane * 4);
    float s = a.x * a.x + a.y * a.y + a.z * a.z + a.w * a.w;
    s = wave_reduce_sum(s);
    if (lane == 0) sq[row] = s;
}

// Kernel 3: main triplet sampling. One wave per anchor.
__global__ __launch_bounds__(256) void triplet_kernel(
    const float* __restrict__ hd, const int* __restrict__ tgt,
    const float* __restrict__ margin_p, const float* __restrict__ u_pos,
    const float* __restrict__ u_neg, const float* __restrict__ sq,
    const int* __restrict__ cnt, float* __restrict__ out)
{
    const int lane = threadIdx.x & 63;
    const int i    = blockIdx.x * 4 + (threadIdx.x >> 6);

    // anchor row in registers (float4 per lane: 64*4 = 256 = D)
    const float4 a = *reinterpret_cast<const float4*>(hd + i * BD + lane * 4);
    const float sqi = sq[i];

    const int ng = *cnt;
    const int ti = tgt[i];
    const int len_pos = (ti == 0) ? ng : (BN - ng);
    const int len_neg = (ti == 0) ? (BN - ng) : ng;

    // positive index — exact integer/fp32 replication of the reference
    const bool excl = (i < len_pos);
    const int  eff  = len_pos - (excl ? 1 : 0);
    const float up  = u_pos[i];
    int u = (int)(up * (float)eff);        // fp32 multiply, trunc toward zero (u >= 0)
    u = min(u, eff - 1);
    const int pos_idx = u + ((excl && (u >= i)) ? 1 : 0);

    // dst_pos = (sq_i - 2*dot) + sq_j  (match numpy association)
    const float4 bp = *reinterpret_cast<const float4*>(hd + pos_idx * BD + lane * 4);
    float pp = a.x * bp.x + a.y * bp.y + a.z * bp.z + a.w * bp.w;
    const float dot_pos = wave_reduce_sum(pp);
    const float dst_pos = (sqi - 2.0f * dot_pos) + sq[pos_idx];

    const float margin = margin_p[0];
    const float lnf    = (float)len_neg;
    const int   lnm1   = len_neg - 1;

    // sequential scan of negative trials, break at first semi-hard hit;
    // running strict-< argmin as the no-hit fallback (first-occurrence).
    int   chosen = -1;
    float best   = __builtin_inff();
    int   best_c = 0;
    const float* unrow = u_neg + i * NTRIALS;
    for (int t = 0; t < NTRIALS; ++t) {
        int c = (int)(unrow[t] * lnf);     // fp32 multiply, trunc
        c = min(c, lnm1);
        const float4 bj = *reinterpret_cast<const float4*>(hd + c * BD + lane * 4);
        float p = a.x * bj.x + a.y * bj.y + a.z * bj.z + a.w * bj.w;
        const float dn = (sqi - 2.0f * wave_reduce_sum(p)) + sq[c];
        const float z = dst_pos - dn;
        if ((z < 0.0f) && (z + margin > 0.0f)) { chosen = c; break; }
        if (dn < best) { best = dn; best_c = c; }
    }
    if (chosen < 0) chosen = best_c;

    // out[i] = {hd[i], hd[pos_idx], hd[chosen]}  -> [N, 3, D]
    float* orow = out + i * (3 * BD);
    *reinterpret_cast<float4*>(orow + lane * 4) = a;
    *reinterpret_cast<float4*>(orow + BD + lane * 4) = bp;
    const float4 bn = *reinterpret_cast<const float4*>(hd + chosen * BD + lane * 4);
    *reinterpret_cast<float4*>(orow + 2 * BD + lane * 4) = bn;
}

extern "C" void kernel_launch(void* const* d_in, const int* in_sizes, int n_in,
                              void* d_out, int out_size, void* d_ws, size_t ws_size,
                              hipStream_t stream) {
    const float* hd     = (const float*)d_in[0];
    const int*   tgt    = (const int*)d_in[1];
    const float* margin = (const float*)d_in[2];
    const float* u_pos  = (const float*)d_in[3];
    const float* u_neg  = (const float*)d_in[4];
    float* out = (float*)d_out;

    float* sq  = (float*)d_ws;
    int*   cnt = (int*)((char*)d_ws + BN * sizeof(float));

    count_genuine_kernel<<<1, 1024, 0, stream>>>(tgt, cnt);
    sqnorm_kernel<<<BN / 4, 256, 0, stream>>>(hd, sq);
    triplet_kernel<<<BN / 4, 256, 0, stream>>>(hd, tgt, margin, u_pos, u_neg, sq, cnt, out);
}

// Round 4
// 112.627 us; speedup vs baseline: 1.0885x; 1.0885x over previous
//
#include <hip/hip_runtime.h>

#define BN 8192
#define BD 256
#define NTRIALS 150

__device__ __forceinline__ float wave_reduce_sum(float v) {
    #pragma unroll
    for (int m = 32; m > 0; m >>= 1) v += __shfl_xor(v, m, 64);
    return v;
}

// Kernel 1: count genuine (tgt == 0). Single block. (verbatim from passing R1)
__global__ __launch_bounds__(1024) void count_genuine_kernel(
    const int* __restrict__ tgt, int* __restrict__ cnt)
{
    __shared__ int lds[16];
    const int t = threadIdx.x;
    int c = 0;
    for (int i = t; i < BN; i += 1024) c += (tgt[i] == 0) ? 1 : 0;
    #pragma unroll
    for (int m = 32; m > 0; m >>= 1) c += __shfl_xor(c, m, 64);
    if ((t & 63) == 0) lds[t >> 6] = c;
    __syncthreads();
    if (t == 0) {
        int s = 0;
        #pragma unroll
        for (int w = 0; w < 16; ++w) s += lds[w];
        *cnt = s;
    }
}

// Kernel 2: sq[i] = sum_d hd[i][d]^2. One wave per row. (verbatim from passing R1)
__global__ __launch_bounds__(256) void sqnorm_kernel(
    const float* __restrict__ hd, float* __restrict__ sq)
{
    const int lane = threadIdx.x & 63;
    const int row  = blockIdx.x * 4 + (threadIdx.x >> 6);
    const float4 a = *reinterpret_cast<const float4*>(hd + row * BD + lane * 4);
    float s = a.x * a.x + a.y * a.y + a.z * a.z + a.w * a.w;
    s = wave_reduce_sum(s);
    if (lane == 0) sq[row] = s;
}

// One trial: process slot (c,bj,sqc) as trial TT; prefetch trial PFT into the
// same slot. The dot/reduce/dn/compare sequence is the exact R1 AST, alone in
// its basic block (the prefetch is independent loads the scheduler hoists).
#define TRIAL_STEP(CSLOT, BJSLOT, SQSLOT, PFT)                                  \
    {                                                                           \
        const int    c_  = CSLOT;                                               \
        const float4 bj  = BJSLOT;                                              \
        const float  sqc = SQSLOT;                                              \
        if ((PFT) < NTRIALS) {                                                  \
            int c2 = (int)(unrow[PFT] * lnf);                                   \
            c2 = min(c2, lnm1);                                                 \
            CSLOT  = c2;                                                        \
            BJSLOT = *reinterpret_cast<const float4*>(hd + c2 * BD + lane * 4); \
            SQSLOT = sq[c2];                                                    \
        }                                                                       \
        float p = a.x * bj.x + a.y * bj.y + a.z * bj.z + a.w * bj.w;            \
        const float dn = (sqi - 2.0f * wave_reduce_sum(p)) + sqc;               \
        const float z = dst_pos - dn;                                           \
        if ((z < 0.0f) && (z + margin > 0.0f)) { chosen = c_; goto done; }      \
        if (dn < best) { best = dn; best_c = c_; }                              \
    }

// Kernel 3: main triplet sampling. One wave per anchor (R1 structure),
// sequential trial scan with depth-2 prefetch pipeline.
__global__ __launch_bounds__(256) void triplet_kernel(
    const float* __restrict__ hd, const int* __restrict__ tgt,
    const float* __restrict__ margin_p, const float* __restrict__ u_pos,
    const float* __restrict__ u_neg, const float* __restrict__ sq,
    const int* __restrict__ cnt, float* __restrict__ out)
{
    const int lane = threadIdx.x & 63;
    const int i    = blockIdx.x * 4 + (threadIdx.x >> 6);

    // anchor row in registers (float4 per lane: 64*4 = 256 = D)
    const float4 a = *reinterpret_cast<const float4*>(hd + i * BD + lane * 4);
    const float sqi = sq[i];

    const int ng = *cnt;
    const int ti = tgt[i];
    const int len_pos = (ti == 0) ? ng : (BN - ng);
    const int len_neg = (ti == 0) ? (BN - ng) : ng;

    // positive index — exact integer/fp32 replication of the reference
    const bool excl = (i < len_pos);
    const int  eff  = len_pos - (excl ? 1 : 0);
    const float up  = u_pos[i];
    int u = (int)(up * (float)eff);        // fp32 multiply, trunc toward zero
    u = min(u, eff - 1);
    const int pos_idx = u + ((excl && (u >= i)) ? 1 : 0);

    // dst_pos = (sq_i - 2*dot) + sq_j  (same expression/order as R1)
    const float4 bp = *reinterpret_cast<const float4*>(hd + pos_idx * BD + lane * 4);
    float pp = a.x * bp.x + a.y * bp.y + a.z * bp.z + a.w * bp.w;
    const float dot_pos = wave_reduce_sum(pp);
    const float dst_pos = (sqi - 2.0f * dot_pos) + sq[pos_idx];

    // write anchor + positive rows now (overlaps with the scan)
    float* orow = out + i * (3 * BD);
    *reinterpret_cast<float4*>(orow + lane * 4) = a;
    *reinterpret_cast<float4*>(orow + BD + lane * 4) = bp;

    const float margin = margin_p[0];
    const float lnf    = (float)len_neg;
    const int   lnm1   = len_neg - 1;

    int   chosen = -1;
    float best   = __builtin_inff();
    int   best_c = 0;
    const float* unrow = u_neg + i * NTRIALS;

    // prologue: prefetch trials 0 (slot A) and 1 (slot B)
    int cA, cB; float4 bjA, bjB; float sqA, sqB;
    {
        int c = (int)(unrow[0] * lnf);
        c = min(c, lnm1);
        cA = c;
        bjA = *reinterpret_cast<const float4*>(hd + c * BD + lane * 4);
        sqA = sq[c];
    }
    {
        int c = (int)(unrow[1] * lnf);
        c = min(c, lnm1);
        cB = c;
        bjB = *reinterpret_cast<const float4*>(hd + c * BD + lane * 4);
        sqB = sq[c];
    }

    for (int t = 0; t < NTRIALS; t += 2) {
        TRIAL_STEP(cA, bjA, sqA, t + 2)   // trial t
        TRIAL_STEP(cB, bjB, sqB, t + 3)   // trial t+1
    }
done:
    ;
    const int neg = (chosen >= 0) ? chosen : best_c;

    const float4 bn = *reinterpret_cast<const float4*>(hd + neg * BD + lane * 4);
    *reinterpret_cast<float4*>(orow + 2 * BD + lane * 4) = bn;
}

extern "C" void kernel_launch(void* const* d_in, const int* in_sizes, int n_in,
                              void* d_out, int out_size, void* d_ws, size_t ws_size,
                              hipStream_t stream) {
    const float* hd     = (const float*)d_in[0];
    const int*   tgt    = (const int*)d_in[1];
    const float* margin = (const float*)d_in[2];
    const float* u_pos  = (const float*)d_in[3];
    const float* u_neg  = (const float*)d_in[4];
    float* out = (float*)d_out;

    float* sq  = (float*)d_ws;
    int*   cnt = (int*)((char*)d_ws + BN * sizeof(float));

    count_genuine_kernel<<<1, 1024, 0, stream>>>(tgt, cnt);
    sqnorm_kernel<<<BN / 4, 256, 0, stream>>>(hd, sq);
    triplet_kernel<<<BN / 4, 256, 0, stream>>>(hd, tgt, margin, u_pos, u_neg, sq, cnt, out);
}